// Round 9
// baseline (460.518 us; speedup 1.0000x reference)
//
#include <hip/hip_runtime.h>
#include <hip/hip_fp16.h>

#define D 64
#define TB 256

// Bucketing: users 1024 nodes/bucket, artists 256 nodes/bucket.
#define BSHIFT_U 10
#define BSHIFT_A 8
#define CAP   12288   // csr per-bucket capacity (actual edges)
#define CAP_P 16384   // part per-bucket capacity (line-padded)
#define SENT  0xFFFFFFFFu

typedef _Float16 half8 __attribute__((ext_vector_type(8)));
typedef float float8 __attribute__((ext_vector_type(8)));
typedef float f32x4 __attribute__((ext_vector_type(4)));

__device__ __forceinline__ float8 h8_to_f8(half8 h) {
    return __builtin_convertvector(h, float8);
}
template <typename T>
__device__ __forceinline__ T ntl(const T* p) { return __builtin_nontemporal_load(p); }
template <typename T>
__device__ __forceinline__ void nts(T* p, T v) { __builtin_nontemporal_store(v, p); }

// fp32 -> fp16 dim-split conversion ([NA][64] -> [2][NA][32]) + zero bcur.
__global__ __launch_bounds__(TB) void cvt_split_zero_kernel(const f32x4* __restrict__ in,
                                                            half8* __restrict__ out, int NA,
                                                            int* __restrict__ bcur, int nb) {
    int i = blockIdx.x * blockDim.x + threadIdx.x;
    int stride = gridDim.x * blockDim.x;
    for (int j = i; j < nb; j += stride) bcur[j] = 0;
    int n8 = NA * 8;
    for (int j = i; j < n8; j += stride) {
        int a = j >> 3, k = j & 7;
        f32x4 x0 = in[a * 16 + k * 2];
        f32x4 x1 = in[a * 16 + k * 2 + 1];
        half8 h;
        h[0] = (_Float16)x0[0]; h[1] = (_Float16)x0[1]; h[2] = (_Float16)x0[2]; h[3] = (_Float16)x0[3];
        h[4] = (_Float16)x1[0]; h[5] = (_Float16)x1[1]; h[6] = (_Float16)x1[2]; h[7] = (_Float16)x1[3];
        out[(size_t)(k >> 2) * (NA * 4) + a * 4 + (k & 3)] = h;
    }
}

// Line-owned padded partition (unchanged from R8): per-block bucket claims are
// rounded to whole 64B lines so each part line has exactly one writer block.
__global__ __launch_bounds__(TB) void partition_both_kernel(const int* __restrict__ art,
                                                            const int* __restrict__ usr, int E,
                                                            int* __restrict__ bcur_u,
                                                            int* __restrict__ bcur_a,
                                                            unsigned* __restrict__ part_u,
                                                            unsigned* __restrict__ part_a,
                                                            int NBu, int NBa) {
    __shared__ int cu[256], bu[256], ca[256], ba[256];
    for (int i = threadIdx.x; i < NBu; i += TB) cu[i] = 0;
    for (int i = threadIdx.x; i < NBa; i += TB) ca[i] = 0;
    __syncthreads();
    int chunk = (E + gridDim.x - 1) / gridDim.x;
    int e0 = blockIdx.x * chunk;
    int e1 = min(E, e0 + chunk);
    for (int e = e0 + threadIdx.x; e < e1; e += TB) {
        atomicAdd(&cu[usr[e] >> BSHIFT_U], 1);
        atomicAdd(&ca[art[e] >> BSHIFT_A], 1);
    }
    __syncthreads();
    for (int i = threadIdx.x; i < NBu; i += TB) {
        int c = cu[i];
        bu[i] = c ? (i * CAP_P + atomicAdd(&bcur_u[i], (c + 15) & ~15)) : 0;
        cu[i] = 0;
    }
    for (int i = threadIdx.x; i < NBa; i += TB) {
        int c = ca[i];
        ba[i] = c ? (i * CAP_P + atomicAdd(&bcur_a[i], (c + 15) & ~15)) : 0;
        ca[i] = 0;
    }
    __syncthreads();
    for (int e = e0 + threadIdx.x; e < e1; e += TB) {
        int a = art[e];
        int u = usr[e];
        int bui = u >> BSHIFT_U;
        int lu = atomicAdd(&cu[bui], 1);
        part_u[bu[bui] + lu] = ((unsigned)a << BSHIFT_U) | ((unsigned)u & ((1u << BSHIFT_U) - 1u));
        int bai = a >> BSHIFT_A;
        int la = atomicAdd(&ca[bai], 1);
        part_a[ba[bai] + la] = ((unsigned)u << BSHIFT_A) | ((unsigned)a & ((1u << BSHIFT_A) - 1u));
    }
    __syncthreads();
    for (int i = threadIdx.x; i < NBu; i += TB) {
        int c = cu[i];
        if (c) {
            int pad = (c + 15) & ~15;
            for (int k = c; k < pad; ++k) part_u[bu[i] + k] = SENT;
        }
    }
    for (int i = threadIdx.x; i < NBa; i += TB) {
        int c = ca[i];
        if (c) {
            int pad = (c + 15) & ~15;
            for (int k = c; k < pad; ++k) part_a[ba[i] + k] = SENT;
        }
    }
}

// Sentinel-aware per-bucket CSR build (unchanged from R8).
__device__ __forceinline__ void local_csr_body(const unsigned* __restrict__ part,
                                               int ecount, int ebeg_p, int ebeg_c, int n0,
                                               int2* __restrict__ rowdeg,
                                               int* __restrict__ csr,
                                               int N, int NPB, int BSHIFT,
                                               int* cnt, int* sdata) {
    const int tid = threadIdx.x;
    const int eend = ebeg_p + ecount;
    const unsigned mask = (unsigned)(NPB - 1);
    for (int i = tid; i < NPB; i += TB) cnt[i] = 0;
    __syncthreads();
    for (int e = ebeg_p + tid; e < eend; e += TB) {
        unsigned r = part[e];
        if (r != SENT) atomicAdd(&cnt[r & mask], 1);
    }
    __syncthreads();
    const int ITEMS = NPB >> 8;
    const int ib = tid * ITEMS;
    int local = 0;
    for (int k = 0; k < ITEMS; ++k) local += cnt[ib + k];
    sdata[tid] = local;
    __syncthreads();
    for (int off = 1; off < TB; off <<= 1) {
        int t = (tid >= off) ? sdata[tid - off] : 0;
        __syncthreads();
        if (tid >= off) sdata[tid] += t;
        __syncthreads();
    }
    int run = sdata[tid] - local;
    for (int k = 0; k < ITEMS; ++k) {
        int v = cnt[ib + k];
        cnt[ib + k] = run;
        int n = n0 + ib + k;
        if (n < N) rowdeg[n] = make_int2(ebeg_c + run, v);
        run += v;
    }
    __syncthreads();
    for (int e = ebeg_p + tid; e < eend; e += TB) {
        unsigned r = part[e];
        if (r == SENT) continue;
        int l = (int)(r & mask);
        int pos = atomicAdd(&cnt[l], 1);
        csr[ebeg_c + pos] = (int)(r >> BSHIFT);
    }
}

__global__ __launch_bounds__(TB) void local_csr_both_kernel(const unsigned* __restrict__ part_u,
                                                            const unsigned* __restrict__ part_a,
                                                            const int* __restrict__ bcur_u,
                                                            const int* __restrict__ bcur_a,
                                                            int2* __restrict__ rowdeg_u,
                                                            int2* __restrict__ rowdeg_a,
                                                            int* __restrict__ csr_u,
                                                            int* __restrict__ csr_a,
                                                            int NU, int NA, int NBu) {
    __shared__ int cnt[1024];
    __shared__ int sdata[TB];
    const int b = blockIdx.x;
    if (b < NBu) {
        local_csr_body(part_u, bcur_u[b], b * CAP_P, b * CAP, b << BSHIFT_U,
                       rowdeg_u, csr_u, NU, 1 << BSHIFT_U, BSHIFT_U, cnt, sdata);
    } else {
        const int bb = b - NBu;
        local_csr_body(part_a, bcur_a[bb], bb * CAP_P, bb * CAP, bb << BSHIFT_A,
                       rowdeg_a, csr_a, NA, 1 << BSHIFT_A, BSHIFT_A, cnt, sdata);
    }
}

// Dim-split user gather (users <- artists), one 32-dim half per pass.
// 4-lane groups (lane = half8 chunk within the half), 16 nodes/wave.
// Source half-table = 3.2MB -> per-XCD L2-resident; all streaming traffic NT.
__global__ __launch_bounds__(TB) void gather_user_kernel(const half8* __restrict__ srcp,  // [NA][4] half p
                                                         const int* __restrict__ csr,
                                                         const int2* __restrict__ rowdeg,
                                                         half8* __restrict__ x_out,      // unsplit [NU][8]
                                                         const f32x4* __restrict__ fin_in0,
                                                         const half8* __restrict__ fin_x1,
                                                         const half8* __restrict__ fin_x2,
                                                         f32x4* __restrict__ fin_out,
                                                         f32x4* __restrict__ final_acc,
                                                         const f32x4* __restrict__ init_src,
                                                         int N, int p, float scale) {
    const int lane = threadIdx.x & 3;
    int g = (blockIdx.x * blockDim.x + threadIdx.x) >> 2;
    const int ngroups = (gridDim.x * blockDim.x) >> 2;
    for (int n = g; n < N; n += ngroups) {
        const long long rdl = ntl((const long long*)&rowdeg[n]);
        const int beg = (int)(unsigned)(rdl & 0xFFFFFFFFll);
        const int dg  = (int)(rdl >> 32);
        const int end = beg + dg;
        float8 a0 = 0.f, a1 = 0.f, a2 = 0.f, a3 = 0.f;
        int e = beg;
        for (; e + 4 <= end; e += 4) {
            const int s0 = ntl(&csr[e + 0]);
            const int s1 = ntl(&csr[e + 1]);
            const int s2 = ntl(&csr[e + 2]);
            const int s3 = ntl(&csr[e + 3]);
            a0 += h8_to_f8(srcp[s0 * 4 + lane]);
            a1 += h8_to_f8(srcp[s1 * 4 + lane]);
            a2 += h8_to_f8(srcp[s2 * 4 + lane]);
            a3 += h8_to_f8(srcp[s3 * 4 + lane]);
        }
        for (; e < end; ++e)
            a0 += h8_to_f8(srcp[ntl(&csr[e]) * 4 + lane]);
        float8 s = (a0 + a1) + (a2 + a3);
        const float inv = 1.f / (float)(dg > 0 ? dg : 1);
        float8 x = s * inv;
        const int xo = n * 8 + p * 4 + lane;   // unsplit half8 index
        if (x_out != nullptr) {
            half8 h;
            for (int k = 0; k < 8; ++k) h[k] = (_Float16)x[k];
            nts(&x_out[xo], h);
        }
        const int fo = n * 16 + p * 8 + lane * 2;  // f32x4 index
        if (fin_out != nullptr) {
            float8 t = h8_to_f8(ntl(&fin_x1[xo])) + h8_to_f8(ntl(&fin_x2[xo])) + x;
            f32x4 f0 = ntl(&fin_in0[fo + 0]);
            f32x4 f1 = ntl(&fin_in0[fo + 1]);
            f32x4 t0 = {t[0], t[1], t[2], t[3]};
            f32x4 t1 = {t[4], t[5], t[6], t[7]};
            nts(&fin_out[fo + 0], (f0 + t0) * scale);
            nts(&fin_out[fo + 1], (f1 + t1) * scale);
        }
        if (final_acc != nullptr) {
            f32x4 f0, f1;
            if (init_src != nullptr) {
                f0 = ntl(&init_src[fo + 0]) * scale;
                f1 = ntl(&init_src[fo + 1]) * scale;
            } else {
                f0 = final_acc[fo + 0];
                f1 = final_acc[fo + 1];
            }
            f32x4 x0 = {x[0], x[1], x[2], x[3]};
            f32x4 x1 = {x[4], x[5], x[6], x[7]};
            final_acc[fo + 0] = f0 + x0 * scale;
            final_acc[fo + 1] = f1 + x1 * scale;
        }
    }
}

// Artist gather (artists <- users): 8-lane groups, unsplit 128B source rows,
// output written in dim-split layout ([2][NA][32]); streaming traffic NT.
__global__ __launch_bounds__(TB) void gather_artist_kernel(const half8* __restrict__ src,  // x_u [NU][8]
                                                           const int* __restrict__ csr,
                                                           const int2* __restrict__ rowdeg,
                                                           half8* __restrict__ x_out_split, // [2][NA][4]
                                                           const f32x4* __restrict__ fin_in0,
                                                           const half8* __restrict__ fin_x1, // split
                                                           const half8* __restrict__ fin_x2, // split
                                                           f32x4* __restrict__ fin_out,
                                                           f32x4* __restrict__ final_acc,
                                                           const f32x4* __restrict__ init_src,
                                                           int N, int split_stride, float scale) {
    const int lane = threadIdx.x & 7;
    int g = (blockIdx.x * blockDim.x + threadIdx.x) >> 3;
    const int ngroups = (gridDim.x * blockDim.x) >> 3;
    for (int n = g; n < N; n += ngroups) {
        const long long rdl = ntl((const long long*)&rowdeg[n]);
        const int beg = (int)(unsigned)(rdl & 0xFFFFFFFFll);
        const int dg  = (int)(rdl >> 32);
        const int end = beg + dg;
        float8 a0 = 0.f, a1 = 0.f, a2 = 0.f, a3 = 0.f;
        int e = beg;
        for (; e + 4 <= end; e += 4) {
            const int s0 = ntl(&csr[e + 0]);
            const int s1 = ntl(&csr[e + 1]);
            const int s2 = ntl(&csr[e + 2]);
            const int s3 = ntl(&csr[e + 3]);
            a0 += h8_to_f8(src[s0 * 8 + lane]);
            a1 += h8_to_f8(src[s1 * 8 + lane]);
            a2 += h8_to_f8(src[s2 * 8 + lane]);
            a3 += h8_to_f8(src[s3 * 8 + lane]);
        }
        for (; e < end; ++e)
            a0 += h8_to_f8(src[ntl(&csr[e]) * 8 + lane]);
        float8 s = (a0 + a1) + (a2 + a3);
        const float inv = 1.f / (float)(dg > 0 ? dg : 1);
        float8 x = s * inv;
        const int sidx = (lane >> 2) * split_stride + n * 4 + (lane & 3);  // dim-split index
        if (x_out_split != nullptr) {
            half8 h;
            for (int k = 0; k < 8; ++k) h[k] = (_Float16)x[k];
            nts(&x_out_split[sidx], h);
        }
        const int fo = n * 16 + lane * 2;  // f32x4 index (unsplit fp32 row)
        if (fin_out != nullptr) {
            float8 t = h8_to_f8(ntl(&fin_x1[sidx])) + h8_to_f8(ntl(&fin_x2[sidx])) + x;
            f32x4 f0 = ntl(&fin_in0[fo + 0]);
            f32x4 f1 = ntl(&fin_in0[fo + 1]);
            f32x4 t0 = {t[0], t[1], t[2], t[3]};
            f32x4 t1 = {t[4], t[5], t[6], t[7]};
            nts(&fin_out[fo + 0], (f0 + t0) * scale);
            nts(&fin_out[fo + 1], (f1 + t1) * scale);
        }
        if (final_acc != nullptr) {
            f32x4 f0, f1;
            if (init_src != nullptr) {
                f0 = ntl(&init_src[fo + 0]) * scale;
                f1 = ntl(&init_src[fo + 1]) * scale;
            } else {
                f0 = final_acc[fo + 0];
                f1 = final_acc[fo + 1];
            }
            f32x4 x0 = {x[0], x[1], x[2], x[3]};
            f32x4 x1 = {x[4], x[5], x[6], x[7]};
            final_acc[fo + 0] = f0 + x0 * scale;
            final_acc[fo + 1] = f1 + x1 * scale;
        }
    }
}

extern "C" void kernel_launch(void* const* d_in, const int* in_sizes, int n_in,
                              void* d_out, int out_size, void* d_ws, size_t ws_size,
                              hipStream_t stream) {
    const float* x_users   = (const float*)d_in[0];
    const float* x_artists = (const float*)d_in[1];
    const int*   a2u       = (const int*)d_in[2];  // row0: artist(src), row1: user(dst)

    const int NU = in_sizes[0] / D;
    const int NA = in_sizes[1] / D;
    const int E  = in_sizes[2] / 2;
    const int* art = a2u;
    const int* usr = a2u + E;

    const float scale = 0.25f;   // 1/(NUM_LAYERS+1)

    const int NBu = (NU + (1 << BSHIFT_U) - 1) >> BSHIFT_U;  // 196
    const int NBa = (NA + (1 << BSHIFT_A) - 1) >> BSHIFT_A;  // 196
    const int SPLIT_STRIDE = NA * 4;  // half8 units per dim-half

    // ---- workspace layout (256B aligned) ----
    char* w = (char*)d_ws;
    size_t off = 0;
    auto alloc = [&](size_t bytes) -> char* {
        char* p = w + off;
        off += (bytes + 255) & ~(size_t)255;
        return p;
    };
    int2* rowdeg_u = (int2*)alloc((size_t)NU * 8);
    int2* rowdeg_a = (int2*)alloc((size_t)NA * 8);
    int* bcur      = (int*)alloc((size_t)(NBu + NBa) * 4);
    int* bcur_u    = bcur;
    int* bcur_a    = bcur + NBu;
    int* csr_u     = (int*)alloc((size_t)NBu * CAP * 4);
    int* csr_a     = (int*)alloc((size_t)NBa * CAP * 4);
    half8* xa_in   = (half8*)alloc((size_t)NA * D * 2);   // dim-split [2][NA][32]
    unsigned* part_u = (unsigned*)alloc((size_t)NBu * CAP_P * 4);
    unsigned* part_a = (unsigned*)alloc((size_t)NBa * CAP_P * 4);

    const size_t XU = (size_t)NU * D * 2;                 // 25.6 MB
    const size_t XA = (size_t)NA * D * 2;                 // 6.4 MB (dim-split total)
    const size_t XUa = (XU + 255) & ~(size_t)255;
    const size_t XAa = (XA + 255) & ~(size_t)255;

    const bool modeA = (off + 3 * XUa) <= ws_size;

    half8* x_u1 = (half8*)alloc(XU);
    half8* x_u2 = modeA ? (half8*)alloc(XU) : x_u1;
    half8* x_u3 = modeA ? (half8*)alloc(XU) : x_u1;
    // x_a dim-split buffers overlay the dead part region (need <= 12.8MB of 25.7MB)
    char* part_base = (char*)part_u;
    half8* x_a1 = (half8*)(part_base);
    half8* x_a2 = modeA ? (half8*)(part_base + XAa) : x_a1;

    float* out_u = (float*)d_out;
    float* out_a = out_u + (size_t)NU * D;

    // ---- fp16 dim-split conversion (+bcur zero) + bucketed CSR build ----
    cvt_split_zero_kernel<<<1024, TB, 0, stream>>>((const f32x4*)x_artists, xa_in, NA,
                                                   bcur, NBu + NBa);
    partition_both_kernel<<<256, TB, 0, stream>>>(art, usr, E, bcur_u, bcur_a,
                                                  part_u, part_a, NBu, NBa);
    local_csr_both_kernel<<<NBu + NBa, TB, 0, stream>>>(part_u, part_a, bcur_u, bcur_a,
                                                        rowdeg_u, rowdeg_a,
                                                        csr_u, csr_a, NU, NA, NBu);

    // ---- 3 propagation layers ----
    half8* xu_buf[3] = {x_u1, x_u2, x_u3};
    half8* xa_buf[3] = {x_a1, x_a2, nullptr};  // l=2 artist writes out only (Mode A)
    const half8* srcA = xa_in;                 // dim-split source table
    for (int l = 0; l < 3; ++l) {
        const bool last = (l == 2);
        // users <- artists : two dim-half passes
        for (int p = 0; p < 2; ++p) {
            gather_user_kernel<<<4096, TB, 0, stream>>>(
                srcA + (size_t)p * SPLIT_STRIDE, csr_u, rowdeg_u, xu_buf[l],
                (modeA && last) ? (const f32x4*)x_users : nullptr,
                (modeA && last) ? x_u1 : nullptr,
                (modeA && last) ? x_u2 : nullptr,
                (modeA && last) ? (f32x4*)out_u : nullptr,
                modeA ? nullptr : (f32x4*)out_u,
                (!modeA && l == 0) ? (const f32x4*)x_users : nullptr,
                NU, p, scale);
        }
        // artists <- users : single pass, dim-split output
        gather_artist_kernel<<<2048, TB, 0, stream>>>(
            xu_buf[l], csr_a, rowdeg_a,
            (modeA && last) ? nullptr : xa_buf[modeA ? l : 0],
            (modeA && last) ? (const f32x4*)x_artists : nullptr,
            (modeA && last) ? x_a1 : nullptr,
            (modeA && last) ? x_a2 : nullptr,
            (modeA && last) ? (f32x4*)out_a : nullptr,
            modeA ? nullptr : (f32x4*)out_a,
            (!modeA && l == 0) ? (const f32x4*)x_artists : nullptr,
            NA, SPLIT_STRIDE, scale);
        srcA = modeA ? xa_buf[l] : xa_buf[0];
        if (modeA && last) srcA = nullptr;  // unused after loop
    }
}

// Round 11
// 359.189 us; speedup vs baseline: 1.2821x; 1.2821x over previous
//
#include <hip/hip_runtime.h>
#include <hip/hip_fp16.h>

#define D 64
#define TB 256

// Bucketing: users 1024 nodes/bucket, artists 256 nodes/bucket.
#define BSHIFT_U 10
#define BSHIFT_A 8
#define CAP   12288   // csr per-bucket capacity (actual edges)
#define CAP_P 16384   // part per-bucket capacity (line-padded)
#define SENT  0xFFFFFFFFu
#define TSHIFT 14     // source-tile shift (16K ids/tile) for sorted CSR

typedef _Float16 half8 __attribute__((ext_vector_type(8)));
typedef float float8 __attribute__((ext_vector_type(8)));
typedef float f32x4 __attribute__((ext_vector_type(4)));

__device__ __forceinline__ float8 h8_to_f8(half8 h) {
    return __builtin_convertvector(h, float8);
}
template <typename T>
__device__ __forceinline__ T ntl(const T* p) { return __builtin_nontemporal_load(p); }
template <typename T>
__device__ __forceinline__ void nts(T* p, T v) { __builtin_nontemporal_store(v, p); }

// fp32 -> fp16 row conversion (8 elems per thread) + zero bucket cursors.
__global__ __launch_bounds__(TB) void cvt_f16_zero_kernel(const f32x4* __restrict__ in,
                                                          half8* __restrict__ out, int n8,
                                                          int* __restrict__ bcur, int nb) {
    int i = blockIdx.x * blockDim.x + threadIdx.x;
    int stride = gridDim.x * blockDim.x;
    for (int j = i; j < nb; j += stride) bcur[j] = 0;
    for (int j = i; j < n8; j += stride) {
        f32x4 a = in[j * 2 + 0];
        f32x4 b = in[j * 2 + 1];
        half8 h;
        h[0] = (_Float16)a[0]; h[1] = (_Float16)a[1]; h[2] = (_Float16)a[2]; h[3] = (_Float16)a[3];
        h[4] = (_Float16)b[0]; h[5] = (_Float16)b[1]; h[6] = (_Float16)b[2]; h[7] = (_Float16)b[3];
        out[j] = h;
    }
}

// Line-owned padded partition (R8): per-block bucket claims rounded to whole
// 64B lines so each part cache line has exactly one writer block.
__global__ __launch_bounds__(TB) void partition_both_kernel(const int* __restrict__ art,
                                                            const int* __restrict__ usr, int E,
                                                            int* __restrict__ bcur_u,
                                                            int* __restrict__ bcur_a,
                                                            unsigned* __restrict__ part_u,
                                                            unsigned* __restrict__ part_a,
                                                            int NBu, int NBa) {
    __shared__ int cu[256], bu[256], ca[256], ba[256];
    for (int i = threadIdx.x; i < NBu; i += TB) cu[i] = 0;
    for (int i = threadIdx.x; i < NBa; i += TB) ca[i] = 0;
    __syncthreads();
    int chunk = (E + gridDim.x - 1) / gridDim.x;
    int e0 = blockIdx.x * chunk;
    int e1 = min(E, e0 + chunk);
    for (int e = e0 + threadIdx.x; e < e1; e += TB) {
        atomicAdd(&cu[usr[e] >> BSHIFT_U], 1);
        atomicAdd(&ca[art[e] >> BSHIFT_A], 1);
    }
    __syncthreads();
    for (int i = threadIdx.x; i < NBu; i += TB) {
        int c = cu[i];
        bu[i] = c ? (i * CAP_P + atomicAdd(&bcur_u[i], (c + 15) & ~15)) : 0;
        cu[i] = 0;
    }
    for (int i = threadIdx.x; i < NBa; i += TB) {
        int c = ca[i];
        ba[i] = c ? (i * CAP_P + atomicAdd(&bcur_a[i], (c + 15) & ~15)) : 0;
        ca[i] = 0;
    }
    __syncthreads();
    for (int e = e0 + threadIdx.x; e < e1; e += TB) {
        int a = art[e];
        int u = usr[e];
        int bui = u >> BSHIFT_U;
        int lu = atomicAdd(&cu[bui], 1);
        part_u[bu[bui] + lu] = ((unsigned)a << BSHIFT_U) | ((unsigned)u & ((1u << BSHIFT_U) - 1u));
        int bai = a >> BSHIFT_A;
        int la = atomicAdd(&ca[bai], 1);
        part_a[ba[bai] + la] = ((unsigned)u << BSHIFT_A) | ((unsigned)a & ((1u << BSHIFT_A) - 1u));
    }
    __syncthreads();
    for (int i = threadIdx.x; i < NBu; i += TB) {
        int c = cu[i];
        if (c) {
            int pad = (c + 15) & ~15;
            for (int k = c; k < pad; ++k) part_u[bu[i] + k] = SENT;
        }
    }
    for (int i = threadIdx.x; i < NBa; i += TB) {
        int c = ca[i];
        if (c) {
            int pad = (c + 15) & ~15;
            for (int k = c; k < pad; ++k) part_a[ba[i] + k] = SENT;
        }
    }
}

// Source-tile-sorted per-bucket CSR build: bin = local_node*NB + (src >> TSHIFT).
// Each node's neighbor list comes out sorted by source tile -> gather-time
// reads sweep the source table in loose lockstep (tile fits per-XCD L2).
template <int NPB, int NB, int BSHIFT>
__device__ __forceinline__ void local_csr_body(const unsigned* __restrict__ part,
                                               int ecount, int ebeg_p, int ebeg_c, int n0,
                                               int2* __restrict__ rowdeg,
                                               int* __restrict__ csr, int N,
                                               int* cnt, int* sdata) {
    const int tid = threadIdx.x;
    const int NBINS = NPB * NB;          // 4096 for both configs
    const int eend = ebeg_p + ecount;
    const unsigned mask = (unsigned)(NPB - 1);
    for (int i = tid; i < NBINS; i += TB) cnt[i] = 0;
    __syncthreads();
    for (int e = ebeg_p + tid; e < eend; e += TB) {
        unsigned r = part[e];
        if (r != SENT) {
            int bin = (int)(r & mask) * NB + (int)((r >> BSHIFT) >> TSHIFT);
            atomicAdd(&cnt[bin], 1);
        }
    }
    __syncthreads();
    const int ITEMS = NBINS / TB;        // 16
    const int ib = tid * ITEMS;
    int local = 0;
    for (int k = 0; k < ITEMS; ++k) local += cnt[ib + k];
    sdata[tid] = local;
    __syncthreads();
    for (int off = 1; off < TB; off <<= 1) {
        int t = (tid >= off) ? sdata[tid - off] : 0;
        __syncthreads();
        if (tid >= off) sdata[tid] += t;
        __syncthreads();
    }
    int run = sdata[tid] - local;
    const int NPT = ITEMS / NB;          // nodes per thread (1 artist / 4 users)
    for (int j = 0; j < NPT; ++j) {
        const int nodeStart = run;
        int d = 0;
        for (int k = 0; k < NB; ++k) {
            int idx = ib + j * NB + k;
            int v = cnt[idx];
            cnt[idx] = run;              // becomes the per-bin fill cursor
            run += v;
            d += v;
        }
        int n = n0 + (ib / NB) + j;
        if (n < N) rowdeg[n] = make_int2(ebeg_c + nodeStart, d);
    }
    __syncthreads();
    for (int e = ebeg_p + tid; e < eend; e += TB) {
        unsigned r = part[e];
        if (r == SENT) continue;
        int bin = (int)(r & mask) * NB + (int)((r >> BSHIFT) >> TSHIFT);
        int pos = atomicAdd(&cnt[bin], 1);
        csr[ebeg_c + pos] = (int)(r >> BSHIFT);
    }
}

// Both directions in one dispatch: blocks [0,NBu) user buckets, rest artists.
__global__ __launch_bounds__(TB) void local_csr_both_kernel(const unsigned* __restrict__ part_u,
                                                            const unsigned* __restrict__ part_a,
                                                            const int* __restrict__ bcur_u,
                                                            const int* __restrict__ bcur_a,
                                                            int2* __restrict__ rowdeg_u,
                                                            int2* __restrict__ rowdeg_a,
                                                            int* __restrict__ csr_u,
                                                            int* __restrict__ csr_a,
                                                            int NU, int NA, int NBu) {
    __shared__ int cnt[4096];
    __shared__ int sdata[TB];
    const int b = blockIdx.x;
    if (b < NBu) {
        // user buckets: 1024 locals x 4 artist-tiles (artist id >>14 in [0,3])
        local_csr_body<1024, 4, BSHIFT_U>(part_u, bcur_u[b], b * CAP_P, b * CAP,
                                          b << BSHIFT_U, rowdeg_u, csr_u, NU, cnt, sdata);
    } else {
        // artist buckets: 256 locals x 16 user-tiles (user id >>14 in [0,12])
        const int bb = b - NBu;
        local_csr_body<256, 16, BSHIFT_A>(part_a, bcur_a[bb], bb * CAP_P, bb * CAP,
                                          bb << BSHIFT_A, rowdeg_a, csr_a, NA, cnt, sdata);
    }
}

// 8-lane group per destination node (lane = half8 chunk); 8 nodes per wave.
// fp16 sources (cacheable), fp32 accumulate.
//  x_out != nullptr    : write fp16 layer output (NORMAL store - re-read later)
//  fin_out != nullptr  : fused final epilogue (Mode A last layer), NT loads/stores
//  final_acc != nullptr: Mode B fused RMW
__global__ __launch_bounds__(TB) void gather_mean_kernel(const half8* __restrict__ src,
                                                         const int* __restrict__ csr,
                                                         const int2* __restrict__ rowdeg,
                                                         half8* __restrict__ x_out,
                                                         f32x4* __restrict__ final_acc,
                                                         const f32x4* __restrict__ init_src,
                                                         const f32x4* __restrict__ fin_in0,
                                                         const half8* __restrict__ fin_x1,
                                                         const half8* __restrict__ fin_x2,
                                                         f32x4* __restrict__ fin_out,
                                                         int N, float scale) {
    const int lane = threadIdx.x & 7;
    int g = (blockIdx.x * blockDim.x + threadIdx.x) >> 3;
    const int ngroups = (gridDim.x * blockDim.x) >> 3;
    for (int n = g; n < N; n += ngroups) {
        const int2 rd = rowdeg[n];
        const int beg = rd.x;
        const int dg = rd.y;
        const int end = beg + dg;
        float8 a0 = 0.f, a1 = 0.f, a2 = 0.f, a3 = 0.f;
        int e = beg;
        for (; e + 4 <= end; e += 4) {
            const int s0 = csr[e + 0];
            const int s1 = csr[e + 1];
            const int s2 = csr[e + 2];
            const int s3 = csr[e + 3];
            a0 += h8_to_f8(src[s0 * 8 + lane]);
            a1 += h8_to_f8(src[s1 * 8 + lane]);
            a2 += h8_to_f8(src[s2 * 8 + lane]);
            a3 += h8_to_f8(src[s3 * 8 + lane]);
        }
        for (; e < end; ++e)
            a0 += h8_to_f8(src[csr[e] * 8 + lane]);
        float8 s = (a0 + a1) + (a2 + a3);
        const float inv = 1.f / (float)(dg > 0 ? dg : 1);
        float8 x = s * inv;
        const int o8 = n * 8 + lane;
        if (x_out != nullptr) {
            half8 h;
            for (int k = 0; k < 8; ++k) h[k] = (_Float16)x[k];
            x_out[o8] = h;
        }
        const int fo = n * (D / 4) + lane * 2;  // f32x4 index into fp32 arrays
        if (fin_out != nullptr) {
            float8 t = h8_to_f8(ntl(&fin_x1[o8])) + h8_to_f8(ntl(&fin_x2[o8])) + x;
            f32x4 f0 = ntl(&fin_in0[fo + 0]);
            f32x4 f1 = ntl(&fin_in0[fo + 1]);
            f32x4 t0 = {t[0], t[1], t[2], t[3]};
            f32x4 t1 = {t[4], t[5], t[6], t[7]};
            nts(&fin_out[fo + 0], (f0 + t0) * scale);
            nts(&fin_out[fo + 1], (f1 + t1) * scale);
        }
        if (final_acc != nullptr) {
            f32x4 f0, f1;
            if (init_src != nullptr) {
                f0 = init_src[fo + 0] * scale;
                f1 = init_src[fo + 1] * scale;
            } else {
                f0 = final_acc[fo + 0];
                f1 = final_acc[fo + 1];
            }
            f32x4 x0 = {x[0], x[1], x[2], x[3]};
            f32x4 x1 = {x[4], x[5], x[6], x[7]};
            final_acc[fo + 0] = f0 + x0 * scale;
            final_acc[fo + 1] = f1 + x1 * scale;
        }
    }
}

extern "C" void kernel_launch(void* const* d_in, const int* in_sizes, int n_in,
                              void* d_out, int out_size, void* d_ws, size_t ws_size,
                              hipStream_t stream) {
    const float* x_users   = (const float*)d_in[0];
    const float* x_artists = (const float*)d_in[1];
    const int*   a2u       = (const int*)d_in[2];  // row0: artist(src), row1: user(dst)

    const int NU = in_sizes[0] / D;
    const int NA = in_sizes[1] / D;
    const int E  = in_sizes[2] / 2;
    const int* art = a2u;
    const int* usr = a2u + E;

    const float scale = 0.25f;   // 1/(NUM_LAYERS+1)

    const int NBu = (NU + (1 << BSHIFT_U) - 1) >> BSHIFT_U;  // 196
    const int NBa = (NA + (1 << BSHIFT_A) - 1) >> BSHIFT_A;  // 196

    // ---- workspace layout (256B aligned) ----
    char* w = (char*)d_ws;
    size_t off = 0;
    auto alloc = [&](size_t bytes) -> char* {
        char* p = w + off;
        off += (bytes + 255) & ~(size_t)255;
        return p;
    };
    int2* rowdeg_u = (int2*)alloc((size_t)NU * 8);
    int2* rowdeg_a = (int2*)alloc((size_t)NA * 8);
    int* bcur      = (int*)alloc((size_t)(NBu + NBa) * 4);
    int* bcur_u    = bcur;
    int* bcur_a    = bcur + NBu;
    int* csr_u     = (int*)alloc((size_t)NBu * CAP * 4);
    int* csr_a     = (int*)alloc((size_t)NBa * CAP * 4);
    half8* xa_in   = (half8*)alloc((size_t)NA * D * 2);   // fp16 copy of x_artists
    unsigned* part_u = (unsigned*)alloc((size_t)NBu * CAP_P * 4);
    unsigned* part_a = (unsigned*)alloc((size_t)NBa * CAP_P * 4);

    const size_t XU = (size_t)NU * D * 2;                 // 25.6 MB
    const size_t XA = (size_t)NA * D * 2;                 // 6.4 MB
    const size_t XUa = (XU + 255) & ~(size_t)255;
    const size_t XAa = (XA + 255) & ~(size_t)255;

    const bool modeA = (off + 3 * XUa) <= ws_size;

    half8* x_u1 = (half8*)alloc(XU);
    half8* x_u2 = modeA ? (half8*)alloc(XU) : x_u1;
    half8* x_u3 = modeA ? (half8*)alloc(XU) : x_u1;
    // x_a buffers overlay the (dead-after-build) part region
    char* part_base = (char*)part_u;
    half8* x_a1 = (half8*)(part_base);
    half8* x_a2 = modeA ? (half8*)(part_base + XAa) : x_a1;

    float* out_u = (float*)d_out;
    float* out_a = out_u + (size_t)NU * D;

    // ---- fp16 conversion (+bcur zero) + line-owned tile-sorted CSR build ----
    cvt_f16_zero_kernel<<<1024, TB, 0, stream>>>((const f32x4*)x_artists, xa_in,
                                                 NA * D / 8, bcur, NBu + NBa);
    partition_both_kernel<<<256, TB, 0, stream>>>(art, usr, E, bcur_u, bcur_a,
                                                  part_u, part_a, NBu, NBa);
    local_csr_both_kernel<<<NBu + NBa, TB, 0, stream>>>(part_u, part_a, bcur_u, bcur_a,
                                                        rowdeg_u, rowdeg_a,
                                                        csr_u, csr_a, NU, NA, NBu);

    // ---- 3 propagation layers ----
    half8* xu_buf[3] = {x_u1, x_u2, x_u3};
    half8* xa_buf[2] = {x_a1, x_a2};           // l=2 artist writes out only (Mode A)
    const half8* srcA = xa_in;
    for (int l = 0; l < 3; ++l) {
        const bool last = (l == 2);
        // users <- artists
        gather_mean_kernel<<<4096, TB, 0, stream>>>(
            srcA, csr_u, rowdeg_u, xu_buf[l],
            modeA ? nullptr : (f32x4*)out_u,
            (!modeA && l == 0) ? (const f32x4*)x_users : nullptr,
            (modeA && last) ? (const f32x4*)x_users : nullptr,
            (modeA && last) ? x_u1 : nullptr,
            (modeA && last) ? x_u2 : nullptr,
            (modeA && last) ? (f32x4*)out_u : nullptr,
            NU, scale);
        // artists <- users
        gather_mean_kernel<<<2048, TB, 0, stream>>>(
            xu_buf[l], csr_a, rowdeg_a,
            (modeA && last) ? nullptr : (modeA ? xa_buf[l] : x_a1),
            modeA ? nullptr : (f32x4*)out_a,
            (!modeA && l == 0) ? (const f32x4*)x_artists : nullptr,
            (modeA && last) ? (const f32x4*)x_artists : nullptr,
            (modeA && last) ? x_a1 : nullptr,
            (modeA && last) ? x_a2 : nullptr,
            (modeA && last) ? (f32x4*)out_a : nullptr,
            NA, scale);
        srcA = modeA ? xa_buf[l < 2 ? l : 0] : x_a1;
    }
}

// Round 12
// 348.318 us; speedup vs baseline: 1.3221x; 1.0312x over previous
//
#include <hip/hip_runtime.h>
#include <hip/hip_fp16.h>

#define D 64
#define TB 256

// Bucketing: users 1024 nodes/bucket, artists 256 nodes/bucket.
#define BSHIFT_U 10
#define BSHIFT_A 8
#define CAP    12288   // part per-bucket capacity (exact counts; mean 10204, ~20 sigma)
#define CAPC_U 16384   // csr user-bucket capacity (x4-padded segments; mean ~11740)
#define CAPC_A 12288   // csr artist-bucket capacity (x4-padded; mean ~10590)
#define TSHIFT 14      // source-tile shift (16K ids/tile) for sorted CSR
#define PCHUNK 4096    // partition LDS sort chunk

typedef _Float16 half8 __attribute__((ext_vector_type(8)));
typedef float float8 __attribute__((ext_vector_type(8)));
typedef float f32x4 __attribute__((ext_vector_type(4)));

__device__ __forceinline__ float8 h8_to_f8(half8 h) {
    return __builtin_convertvector(h, float8);
}
template <typename T>
__device__ __forceinline__ T ntl(const T* p) { return __builtin_nontemporal_load(p); }
template <typename T>
__device__ __forceinline__ void nts(T* p, T v) { __builtin_nontemporal_store(v, p); }

// fp32 -> fp16 row conversion (8 elems per thread) + zero bucket cursors.
__global__ __launch_bounds__(TB) void cvt_f16_zero_kernel(const f32x4* __restrict__ in,
                                                          half8* __restrict__ out, int n8,
                                                          int* __restrict__ bcur, int nb) {
    int i = blockIdx.x * blockDim.x + threadIdx.x;
    int stride = gridDim.x * blockDim.x;
    for (int j = i; j < nb; j += stride) bcur[j] = 0;
    for (int j = i; j < n8; j += stride) {
        f32x4 a = in[j * 2 + 0];
        f32x4 b = in[j * 2 + 1];
        half8 h;
        h[0] = (_Float16)a[0]; h[1] = (_Float16)a[1]; h[2] = (_Float16)a[2]; h[3] = (_Float16)a[3];
        h[4] = (_Float16)b[0]; h[5] = (_Float16)b[1]; h[6] = (_Float16)b[2]; h[7] = (_Float16)b[3];
        out[j] = h;
    }
}

// LDS counting-sort partition: per 4K-edge chunk, sort records by bucket in
// LDS, claim EXACT per-bucket global ranges, wave-per-bucket coalesced copy.
struct PartShared {
    unsigned recs[PCHUNK];
    unsigned sorted[PCHUNK];
    unsigned short loc[PCHUNK];
    unsigned char bkt[PCHUNK];
    int cnt[256];
    int gbase[256];
    int seg[256];
    int scanbuf[TB];
};

__device__ __forceinline__ void part_direction(PartShared& sh, int m, int NB,
                                               int* __restrict__ bcur,
                                               unsigned* __restrict__ part) {
    const int tid = threadIdx.x;
    for (int i = tid; i < NB; i += TB) sh.cnt[i] = 0;
    __syncthreads();
    for (int i = tid; i < m; i += TB)
        sh.loc[i] = (unsigned short)atomicAdd(&sh.cnt[sh.bkt[i]], 1);
    __syncthreads();
    int v = (tid < NB) ? sh.cnt[tid] : 0;
    sh.scanbuf[tid] = v;
    __syncthreads();
    for (int off = 1; off < TB; off <<= 1) {
        int t = (tid >= off) ? sh.scanbuf[tid - off] : 0;
        __syncthreads();
        if (tid >= off) sh.scanbuf[tid] += t;
        __syncthreads();
    }
    if (tid < NB) {
        sh.seg[tid] = sh.scanbuf[tid] - v;
        if (v) sh.gbase[tid] = atomicAdd(&bcur[tid], v);
    }
    __syncthreads();
    for (int i = tid; i < m; i += TB)
        sh.sorted[sh.seg[sh.bkt[i]] + sh.loc[i]] = sh.recs[i];
    __syncthreads();
    // coalesced copy-out: wave per bucket round-robin
    const int wid = tid >> 6;
    const int lane = tid & 63;
    for (int b = wid; b < NB; b += TB / 64) {
        int s = sh.seg[b];
        int send = (b + 1 < NB) ? sh.seg[b + 1] : m;
        if (send <= s) continue;
        unsigned* dst = part + (size_t)b * CAP + sh.gbase[b];
        for (int i = s + lane; i < send; i += 64) dst[i - s] = sh.sorted[i];
    }
    __syncthreads();
}

__global__ __launch_bounds__(TB) void partition_both_kernel(const int* __restrict__ art,
                                                            const int* __restrict__ usr, int E,
                                                            int* __restrict__ bcur_u,
                                                            int* __restrict__ bcur_a,
                                                            unsigned* __restrict__ part_u,
                                                            unsigned* __restrict__ part_a,
                                                            int NBu, int NBa) {
    __shared__ PartShared sh;
    const int tid = threadIdx.x;
    int chunk = (E + gridDim.x - 1) / gridDim.x;
    int e0 = blockIdx.x * chunk;
    int e1 = min(E, e0 + chunk);
    for (int c0 = e0; c0 < e1; c0 += PCHUNK) {
        int m = min(PCHUNK, e1 - c0);
        // direction U: record = (art << 10) | (usr & 1023), bucket = usr >> 10
        for (int i = tid; i < m; i += TB) {
            int a = art[c0 + i], u = usr[c0 + i];
            sh.recs[i] = ((unsigned)a << BSHIFT_U) | ((unsigned)u & ((1u << BSHIFT_U) - 1u));
            sh.bkt[i] = (unsigned char)(u >> BSHIFT_U);
        }
        __syncthreads();
        part_direction(sh, m, NBu, bcur_u, part_u);
        // direction A: record = (usr << 8) | (art & 255), bucket = art >> 8
        for (int i = tid; i < m; i += TB) {
            int a = art[c0 + i], u = usr[c0 + i];
            sh.recs[i] = ((unsigned)u << BSHIFT_A) | ((unsigned)a & ((1u << BSHIFT_A) - 1u));
            sh.bkt[i] = (unsigned char)(a >> BSHIFT_A);
        }
        __syncthreads();
        part_direction(sh, m, NBa, bcur_a, part_a);
    }
}

// Source-tile-sorted per-bucket CSR build with x4-padded node segments.
// bin = local_node*NB + (src >> TSHIFT); dummies (id 0) appended to pad each
// node's segment to a multiple of 4 (gather corrects via row0).
template <int NPB, int NB, int BSHIFT>
__device__ __forceinline__ void local_csr_body(const unsigned* __restrict__ part,
                                               int ecount, int ebeg_p, int ebeg_c, int n0,
                                               int2* __restrict__ rowdeg,
                                               int* __restrict__ csr, int N,
                                               int* cnt, int* sdata) {
    const int tid = threadIdx.x;
    const int NBINS = NPB * NB;          // 4096 for both configs
    const int eend = ebeg_p + ecount;
    const unsigned mask = (unsigned)(NPB - 1);
    for (int i = tid; i < NBINS; i += TB) cnt[i] = 0;
    __syncthreads();
    for (int e = ebeg_p + tid; e < eend; e += TB) {
        unsigned r = part[e];
        int bin = (int)(r & mask) * NB + (int)((r >> BSHIFT) >> TSHIFT);
        atomicAdd(&cnt[bin], 1);
    }
    __syncthreads();
    const int ITEMS = NBINS / TB;        // 16
    const int NPT = ITEMS / NB;          // nodes per thread (4 users / 1 artist)
    const int ib = tid * ITEMS;
    int dj[NPT], pdj[NPT], nsj[NPT];
    int local = 0;
    for (int j = 0; j < NPT; ++j) {
        int d = 0;
        for (int k = 0; k < NB; ++k) d += cnt[ib + j * NB + k];
        dj[j] = d;
        pdj[j] = (d + 3) & ~3;
        local += pdj[j];
    }
    sdata[tid] = local;
    __syncthreads();
    for (int off = 1; off < TB; off <<= 1) {
        int t = (tid >= off) ? sdata[tid - off] : 0;
        __syncthreads();
        if (tid >= off) sdata[tid] += t;
        __syncthreads();
    }
    int run = sdata[tid] - local;
    for (int j = 0; j < NPT; ++j) {
        nsj[j] = run;
        int c = run;
        for (int k = 0; k < NB; ++k) {
            int idx = ib + j * NB + k;
            int v = cnt[idx];
            cnt[idx] = c;                // per-bin fill cursor
            c += v;
        }
        int n = n0 + tid * NPT + j;
        if (n < N) rowdeg[n] = make_int2(ebeg_c + run, dj[j]);
        run += pdj[j];
    }
    __syncthreads();
    for (int e = ebeg_p + tid; e < eend; e += TB) {
        unsigned r = part[e];
        int bin = (int)(r & mask) * NB + (int)((r >> BSHIFT) >> TSHIFT);
        int pos = atomicAdd(&cnt[bin], 1);
        csr[ebeg_c + pos] = (int)(r >> BSHIFT);
    }
    // pad fill: dummy id 0 in [d, pd) of each node segment
    for (int j = 0; j < NPT; ++j)
        for (int k = dj[j]; k < pdj[j]; ++k) csr[ebeg_c + nsj[j] + k] = 0;
}

__global__ __launch_bounds__(TB) void local_csr_both_kernel(const unsigned* __restrict__ part_u,
                                                            const unsigned* __restrict__ part_a,
                                                            const int* __restrict__ bcur_u,
                                                            const int* __restrict__ bcur_a,
                                                            int2* __restrict__ rowdeg_u,
                                                            int2* __restrict__ rowdeg_a,
                                                            int* __restrict__ csr_u,
                                                            int* __restrict__ csr_a,
                                                            int NU, int NA, int NBu) {
    __shared__ int cnt[4096];
    __shared__ int sdata[TB];
    const int b = blockIdx.x;
    if (b < NBu) {
        local_csr_body<1024, 4, BSHIFT_U>(part_u, bcur_u[b], b * CAP, b * CAPC_U,
                                          b << BSHIFT_U, rowdeg_u, csr_u, NU, cnt, sdata);
    } else {
        const int bb = b - NBu;
        local_csr_body<256, 16, BSHIFT_A>(part_a, bcur_a[bb], bb * CAP, bb * CAPC_A,
                                          bb << BSHIFT_A, rowdeg_a, csr_a, NA, cnt, sdata);
    }
}

// 8-lane group per destination node; uniform 4-wide edge loop (x4-padded CSR,
// dummy id 0) + 8-wide unroll -> up to 8 outstanding row loads per wave.
// Correction: sum -= (pd - deg) * row0 (row0 hoisted, L1-hot).
__global__ __launch_bounds__(TB) void gather_mean_kernel(const half8* __restrict__ src,
                                                         const int* __restrict__ csr,
                                                         const int2* __restrict__ rowdeg,
                                                         half8* __restrict__ x_out,
                                                         f32x4* __restrict__ final_acc,
                                                         const f32x4* __restrict__ init_src,
                                                         const f32x4* __restrict__ fin_in0,
                                                         const half8* __restrict__ fin_x1,
                                                         const half8* __restrict__ fin_x2,
                                                         f32x4* __restrict__ fin_out,
                                                         int N, float scale) {
    const int lane = threadIdx.x & 7;
    int g = (blockIdx.x * blockDim.x + threadIdx.x) >> 3;
    const int ngroups = (gridDim.x * blockDim.x) >> 3;
    const float8 r0 = h8_to_f8(src[lane]);   // row 0 (dummy target), hoisted
    for (int n = g; n < N; n += ngroups) {
        const int2 rd = rowdeg[n];
        const int beg = rd.x;
        const int dg = rd.y;
        const int pd = (dg + 3) & ~3;
        const int end = beg + pd;
        float8 a0 = 0.f, a1 = 0.f, a2 = 0.f, a3 = 0.f;
        int e = beg;
        for (; e + 8 <= end; e += 8) {
            const int s0 = csr[e + 0];
            const int s1 = csr[e + 1];
            const int s2 = csr[e + 2];
            const int s3 = csr[e + 3];
            const int s4 = csr[e + 4];
            const int s5 = csr[e + 5];
            const int s6 = csr[e + 6];
            const int s7 = csr[e + 7];
            const half8 v0 = src[s0 * 8 + lane];
            const half8 v1 = src[s1 * 8 + lane];
            const half8 v2 = src[s2 * 8 + lane];
            const half8 v3 = src[s3 * 8 + lane];
            const half8 v4 = src[s4 * 8 + lane];
            const half8 v5 = src[s5 * 8 + lane];
            const half8 v6 = src[s6 * 8 + lane];
            const half8 v7 = src[s7 * 8 + lane];
            a0 += h8_to_f8(v0);
            a1 += h8_to_f8(v1);
            a2 += h8_to_f8(v2);
            a3 += h8_to_f8(v3);
            a0 += h8_to_f8(v4);
            a1 += h8_to_f8(v5);
            a2 += h8_to_f8(v6);
            a3 += h8_to_f8(v7);
        }
        if (e < end) {   // exactly one 4-wide iteration (pd % 4 == 0)
            const int s0 = csr[e + 0];
            const int s1 = csr[e + 1];
            const int s2 = csr[e + 2];
            const int s3 = csr[e + 3];
            a0 += h8_to_f8(src[s0 * 8 + lane]);
            a1 += h8_to_f8(src[s1 * 8 + lane]);
            a2 += h8_to_f8(src[s2 * 8 + lane]);
            a3 += h8_to_f8(src[s3 * 8 + lane]);
        }
        float8 s = (a0 + a1) + (a2 + a3);
        s -= (float)(pd - dg) * r0;
        const float inv = 1.f / (float)(dg > 0 ? dg : 1);
        float8 x = s * inv;
        const int o8 = n * 8 + lane;
        if (x_out != nullptr) {
            half8 h;
            for (int k = 0; k < 8; ++k) h[k] = (_Float16)x[k];
            x_out[o8] = h;
        }
        const int fo = n * (D / 4) + lane * 2;
        if (fin_out != nullptr) {
            float8 t = h8_to_f8(ntl(&fin_x1[o8])) + h8_to_f8(ntl(&fin_x2[o8])) + x;
            f32x4 f0 = ntl(&fin_in0[fo + 0]);
            f32x4 f1 = ntl(&fin_in0[fo + 1]);
            f32x4 t0 = {t[0], t[1], t[2], t[3]};
            f32x4 t1 = {t[4], t[5], t[6], t[7]};
            nts(&fin_out[fo + 0], (f0 + t0) * scale);
            nts(&fin_out[fo + 1], (f1 + t1) * scale);
        }
        if (final_acc != nullptr) {
            f32x4 f0, f1;
            if (init_src != nullptr) {
                f0 = init_src[fo + 0] * scale;
                f1 = init_src[fo + 1] * scale;
            } else {
                f0 = final_acc[fo + 0];
                f1 = final_acc[fo + 1];
            }
            f32x4 x0 = {x[0], x[1], x[2], x[3]};
            f32x4 x1 = {x[4], x[5], x[6], x[7]};
            final_acc[fo + 0] = f0 + x0 * scale;
            final_acc[fo + 1] = f1 + x1 * scale;
        }
    }
}

extern "C" void kernel_launch(void* const* d_in, const int* in_sizes, int n_in,
                              void* d_out, int out_size, void* d_ws, size_t ws_size,
                              hipStream_t stream) {
    const float* x_users   = (const float*)d_in[0];
    const float* x_artists = (const float*)d_in[1];
    const int*   a2u       = (const int*)d_in[2];  // row0: artist(src), row1: user(dst)

    const int NU = in_sizes[0] / D;
    const int NA = in_sizes[1] / D;
    const int E  = in_sizes[2] / 2;
    const int* art = a2u;
    const int* usr = a2u + E;

    const float scale = 0.25f;   // 1/(NUM_LAYERS+1)

    const int NBu = (NU + (1 << BSHIFT_U) - 1) >> BSHIFT_U;  // 196
    const int NBa = (NA + (1 << BSHIFT_A) - 1) >> BSHIFT_A;  // 196

    // ---- workspace layout (256B aligned) ----
    char* w = (char*)d_ws;
    size_t off = 0;
    auto alloc = [&](size_t bytes) -> char* {
        char* p = w + off;
        off += (bytes + 255) & ~(size_t)255;
        return p;
    };
    int2* rowdeg_u = (int2*)alloc((size_t)NU * 8);
    int2* rowdeg_a = (int2*)alloc((size_t)NA * 8);
    int* bcur      = (int*)alloc((size_t)(NBu + NBa) * 4);
    int* bcur_u    = bcur;
    int* bcur_a    = bcur + NBu;
    int* csr_u     = (int*)alloc((size_t)NBu * CAPC_U * 4);
    int* csr_a     = (int*)alloc((size_t)NBa * CAPC_A * 4);
    half8* xa_in   = (half8*)alloc((size_t)NA * D * 2);   // fp16 copy of x_artists
    unsigned* part_u = (unsigned*)alloc((size_t)NBu * CAP * 4);
    unsigned* part_a = (unsigned*)alloc((size_t)NBa * CAP * 4);

    const size_t XU = (size_t)NU * D * 2;                 // 25.6 MB
    const size_t XA = (size_t)NA * D * 2;                 // 6.4 MB
    const size_t XUa = (XU + 255) & ~(size_t)255;
    const size_t XAa = (XA + 255) & ~(size_t)255;

    const bool modeA = (off + 3 * XUa) <= ws_size;

    half8* x_u1 = (half8*)alloc(XU);
    half8* x_u2 = modeA ? (half8*)alloc(XU) : x_u1;
    half8* x_u3 = modeA ? (half8*)alloc(XU) : x_u1;
    // x_a buffers overlay the (dead-after-build) part region (19.2MB >= 12.8MB)
    char* part_base = (char*)part_u;
    half8* x_a1 = (half8*)(part_base);
    half8* x_a2 = modeA ? (half8*)(part_base + XAa) : x_a1;

    float* out_u = (float*)d_out;
    float* out_a = out_u + (size_t)NU * D;

    // ---- fp16 conversion (+bcur zero) + sorted CSR build ----
    cvt_f16_zero_kernel<<<1024, TB, 0, stream>>>((const f32x4*)x_artists, xa_in,
                                                 NA * D / 8, bcur, NBu + NBa);
    partition_both_kernel<<<512, TB, 0, stream>>>(art, usr, E, bcur_u, bcur_a,
                                                  part_u, part_a, NBu, NBa);
    local_csr_both_kernel<<<NBu + NBa, TB, 0, stream>>>(part_u, part_a, bcur_u, bcur_a,
                                                        rowdeg_u, rowdeg_a,
                                                        csr_u, csr_a, NU, NA, NBu);

    // ---- 3 propagation layers ----
    half8* xu_buf[3] = {x_u1, x_u2, x_u3};
    half8* xa_buf[2] = {x_a1, x_a2};           // l=2 artist writes out only (Mode A)
    const half8* srcA = xa_in;
    for (int l = 0; l < 3; ++l) {
        const bool last = (l == 2);
        // users <- artists
        gather_mean_kernel<<<4096, TB, 0, stream>>>(
            srcA, csr_u, rowdeg_u, xu_buf[l],
            modeA ? nullptr : (f32x4*)out_u,
            (!modeA && l == 0) ? (const f32x4*)x_users : nullptr,
            (modeA && last) ? (const f32x4*)x_users : nullptr,
            (modeA && last) ? x_u1 : nullptr,
            (modeA && last) ? x_u2 : nullptr,
            (modeA && last) ? (f32x4*)out_u : nullptr,
            NU, scale);
        // artists <- users
        gather_mean_kernel<<<2048, TB, 0, stream>>>(
            xu_buf[l], csr_a, rowdeg_a,
            (modeA && last) ? nullptr : (modeA ? xa_buf[l] : x_a1),
            modeA ? nullptr : (f32x4*)out_a,
            (!modeA && l == 0) ? (const f32x4*)x_artists : nullptr,
            (modeA && last) ? (const f32x4*)x_artists : nullptr,
            (modeA && last) ? x_a1 : nullptr,
            (modeA && last) ? x_a2 : nullptr,
            (modeA && last) ? (f32x4*)out_a : nullptr,
            NA, scale);
        srcA = modeA ? xa_buf[l < 2 ? l : 0] : x_a1;
    }
}

// Round 13
// 347.329 us; speedup vs baseline: 1.3259x; 1.0028x over previous
//
#include <hip/hip_runtime.h>
#include <hip/hip_fp16.h>

#define D 64
#define TB 256

// Bucketing: users 1024 nodes/bucket, artists 256 nodes/bucket.
#define BSHIFT_U 10
#define BSHIFT_A 8
#define CAP    12288   // part per-bucket capacity (exact counts; mean 10204, ~20 sigma)
#define CAPC_U 16384   // csr user-bucket capacity (x4-padded segments; mean ~11740)
#define CAPC_A 12288   // csr artist-bucket capacity (x4-padded; mean ~10590)
#define TSHIFT 14      // source-tile shift (16K ids/tile) for sorted CSR
#define PCHUNK 4096    // partition LDS sort chunk

typedef _Float16 half8 __attribute__((ext_vector_type(8)));
typedef float float8 __attribute__((ext_vector_type(8)));
typedef float f32x4 __attribute__((ext_vector_type(4)));

__device__ __forceinline__ float8 h8_to_f8(half8 h) {
    return __builtin_convertvector(h, float8);
}
template <typename T>
__device__ __forceinline__ T ntl(const T* p) { return __builtin_nontemporal_load(p); }
template <typename T>
__device__ __forceinline__ void nts(T* p, T v) { __builtin_nontemporal_store(v, p); }

// fp32 -> fp16 row conversion (8 elems per thread).
__global__ __launch_bounds__(TB) void cvt_f16_kernel(const f32x4* __restrict__ in,
                                                     half8* __restrict__ out, int n8) {
    int i = blockIdx.x * blockDim.x + threadIdx.x;
    int stride = gridDim.x * blockDim.x;
    for (int j = i; j < n8; j += stride) {
        f32x4 a = in[j * 2 + 0];
        f32x4 b = in[j * 2 + 1];
        half8 h;
        h[0] = (_Float16)a[0]; h[1] = (_Float16)a[1]; h[2] = (_Float16)a[2]; h[3] = (_Float16)a[3];
        h[4] = (_Float16)b[0]; h[5] = (_Float16)b[1]; h[6] = (_Float16)b[2]; h[7] = (_Float16)b[3];
        out[j] = h;
    }
}

// LDS counting-sort partition, one DIRECTION per block (even=U, odd=A):
// per 4K-edge chunk, sort records by bucket in LDS, claim EXACT per-bucket
// global ranges, wave-per-bucket coalesced copy-out.
struct PartShared {
    unsigned recs[PCHUNK];
    unsigned sorted[PCHUNK];
    unsigned short loc[PCHUNK];
    unsigned char bkt[PCHUNK];
    int cnt[256];
    int gbase[256];
    int seg[256];
    int scanbuf[TB];
};

__device__ __forceinline__ void part_direction(PartShared& sh, int m, int NB,
                                               int* __restrict__ bcur,
                                               unsigned* __restrict__ part) {
    const int tid = threadIdx.x;
    for (int i = tid; i < NB; i += TB) sh.cnt[i] = 0;
    __syncthreads();
    for (int i = tid; i < m; i += TB)
        sh.loc[i] = (unsigned short)atomicAdd(&sh.cnt[sh.bkt[i]], 1);
    __syncthreads();
    int v = (tid < NB) ? sh.cnt[tid] : 0;
    sh.scanbuf[tid] = v;
    __syncthreads();
    for (int off = 1; off < TB; off <<= 1) {
        int t = (tid >= off) ? sh.scanbuf[tid - off] : 0;
        __syncthreads();
        if (tid >= off) sh.scanbuf[tid] += t;
        __syncthreads();
    }
    if (tid < NB) {
        sh.seg[tid] = sh.scanbuf[tid] - v;
        if (v) sh.gbase[tid] = atomicAdd(&bcur[tid], v);
    }
    __syncthreads();
    for (int i = tid; i < m; i += TB)
        sh.sorted[sh.seg[sh.bkt[i]] + sh.loc[i]] = sh.recs[i];
    __syncthreads();
    // coalesced copy-out: wave per bucket round-robin
    const int wid = tid >> 6;
    const int lane = tid & 63;
    for (int b = wid; b < NB; b += TB / 64) {
        int s = sh.seg[b];
        int send = (b + 1 < NB) ? sh.seg[b + 1] : m;
        if (send <= s) continue;
        unsigned* dst = part + (size_t)b * CAP + sh.gbase[b];
        for (int i = s + lane; i < send; i += 64) dst[i - s] = sh.sorted[i];
    }
    __syncthreads();
}

__global__ __launch_bounds__(TB) void partition_both_kernel(const int* __restrict__ art,
                                                            const int* __restrict__ usr, int E,
                                                            int* __restrict__ bcur_u,
                                                            int* __restrict__ bcur_a,
                                                            unsigned* __restrict__ part_u,
                                                            unsigned* __restrict__ part_a,
                                                            int NBu, int NBa) {
    __shared__ PartShared sh;
    const int tid = threadIdx.x;
    const int dir = blockIdx.x & 1;
    const int cidx = blockIdx.x >> 1;
    const int nchunks = gridDim.x >> 1;
    for (int c = cidx; (size_t)c * PCHUNK < (size_t)E; c += nchunks) {
        const int c0 = c * PCHUNK;
        const int m = min(PCHUNK, E - c0);
        if (dir == 0) {
            // direction U: record = (art << 10) | (usr & 1023), bucket = usr >> 10
            for (int i = tid; i < m; i += TB) {
                int a = art[c0 + i], u = usr[c0 + i];
                sh.recs[i] = ((unsigned)a << BSHIFT_U) | ((unsigned)u & ((1u << BSHIFT_U) - 1u));
                sh.bkt[i] = (unsigned char)(u >> BSHIFT_U);
            }
            __syncthreads();
            part_direction(sh, m, NBu, bcur_u, part_u);
        } else {
            // direction A: record = (usr << 8) | (art & 255), bucket = art >> 8
            for (int i = tid; i < m; i += TB) {
                int a = art[c0 + i], u = usr[c0 + i];
                sh.recs[i] = ((unsigned)u << BSHIFT_A) | ((unsigned)a & ((1u << BSHIFT_A) - 1u));
                sh.bkt[i] = (unsigned char)(a >> BSHIFT_A);
            }
            __syncthreads();
            part_direction(sh, m, NBa, bcur_a, part_a);
        }
    }
}

// Source-tile-sorted per-bucket CSR build with x4-padded node segments.
// bin = local_node*NB + (src >> TSHIFT); dummies (id 0) appended to pad each
// node's segment to a multiple of 4 (gather corrects via row0).
template <int NPB, int NB, int BSHIFT>
__device__ __forceinline__ void local_csr_body(const unsigned* __restrict__ part,
                                               int ecount, int ebeg_p, int ebeg_c, int n0,
                                               int2* __restrict__ rowdeg,
                                               int* __restrict__ csr, int N,
                                               int* cnt, int* sdata) {
    const int tid = threadIdx.x;
    const int NBINS = NPB * NB;          // 4096 for both configs
    const int eend = ebeg_p + ecount;
    const unsigned mask = (unsigned)(NPB - 1);
    for (int i = tid; i < NBINS; i += TB) cnt[i] = 0;
    __syncthreads();
    for (int e = ebeg_p + tid; e < eend; e += TB) {
        unsigned r = part[e];
        int bin = (int)(r & mask) * NB + (int)((r >> BSHIFT) >> TSHIFT);
        atomicAdd(&cnt[bin], 1);
    }
    __syncthreads();
    const int ITEMS = NBINS / TB;        // 16
    const int NPT = ITEMS / NB;          // nodes per thread (4 users / 1 artist)
    const int ib = tid * ITEMS;
    int dj[NPT], pdj[NPT], nsj[NPT];
    int local = 0;
    for (int j = 0; j < NPT; ++j) {
        int d = 0;
        for (int k = 0; k < NB; ++k) d += cnt[ib + j * NB + k];
        dj[j] = d;
        pdj[j] = (d + 3) & ~3;
        local += pdj[j];
    }
    sdata[tid] = local;
    __syncthreads();
    for (int off = 1; off < TB; off <<= 1) {
        int t = (tid >= off) ? sdata[tid - off] : 0;
        __syncthreads();
        if (tid >= off) sdata[tid] += t;
        __syncthreads();
    }
    int run = sdata[tid] - local;
    for (int j = 0; j < NPT; ++j) {
        nsj[j] = run;
        int c = run;
        for (int k = 0; k < NB; ++k) {
            int idx = ib + j * NB + k;
            int v = cnt[idx];
            cnt[idx] = c;                // per-bin fill cursor
            c += v;
        }
        int n = n0 + tid * NPT + j;
        if (n < N) rowdeg[n] = make_int2(ebeg_c + run, dj[j]);
        run += pdj[j];
    }
    __syncthreads();
    for (int e = ebeg_p + tid; e < eend; e += TB) {
        unsigned r = part[e];
        int bin = (int)(r & mask) * NB + (int)((r >> BSHIFT) >> TSHIFT);
        int pos = atomicAdd(&cnt[bin], 1);
        csr[ebeg_c + pos] = (int)(r >> BSHIFT);
    }
    // pad fill: dummy id 0 in [d, pd) of each node segment
    for (int j = 0; j < NPT; ++j)
        for (int k = dj[j]; k < pdj[j]; ++k) csr[ebeg_c + nsj[j] + k] = 0;
}

__global__ __launch_bounds__(TB) void local_csr_both_kernel(const unsigned* __restrict__ part_u,
                                                            const unsigned* __restrict__ part_a,
                                                            const int* __restrict__ bcur_u,
                                                            const int* __restrict__ bcur_a,
                                                            int2* __restrict__ rowdeg_u,
                                                            int2* __restrict__ rowdeg_a,
                                                            int* __restrict__ csr_u,
                                                            int* __restrict__ csr_a,
                                                            int NU, int NA, int NBu) {
    __shared__ int cnt[4096];
    __shared__ int sdata[TB];
    const int b = blockIdx.x;
    if (b < NBu) {
        local_csr_body<1024, 4, BSHIFT_U>(part_u, bcur_u[b], b * CAP, b * CAPC_U,
                                          b << BSHIFT_U, rowdeg_u, csr_u, NU, cnt, sdata);
    } else {
        const int bb = b - NBu;
        local_csr_body<256, 16, BSHIFT_A>(part_a, bcur_a[bb], bb * CAP, bb * CAPC_A,
                                          bb << BSHIFT_A, rowdeg_a, csr_a, NA, cnt, sdata);
    }
}

// 8-lane group per destination node; uniform 4-wide edge loop (x4-padded CSR,
// dummy id 0) + 8-wide unroll -> up to 8 outstanding row loads per wave.
// Correction: sum -= (pd - deg) * row0 (row0 hoisted, L1-hot).
__global__ __launch_bounds__(TB) void gather_mean_kernel(const half8* __restrict__ src,
                                                         const int* __restrict__ csr,
                                                         const int2* __restrict__ rowdeg,
                                                         half8* __restrict__ x_out,
                                                         f32x4* __restrict__ final_acc,
                                                         const f32x4* __restrict__ init_src,
                                                         const f32x4* __restrict__ fin_in0,
                                                         const half8* __restrict__ fin_x1,
                                                         const half8* __restrict__ fin_x2,
                                                         f32x4* __restrict__ fin_out,
                                                         int N, float scale) {
    const int lane = threadIdx.x & 7;
    int g = (blockIdx.x * blockDim.x + threadIdx.x) >> 3;
    const int ngroups = (gridDim.x * blockDim.x) >> 3;
    const float8 r0 = h8_to_f8(src[lane]);   // row 0 (dummy target), hoisted
    for (int n = g; n < N; n += ngroups) {
        const int2 rd = rowdeg[n];
        const int beg = rd.x;
        const int dg = rd.y;
        const int pd = (dg + 3) & ~3;
        const int end = beg + pd;
        float8 a0 = 0.f, a1 = 0.f, a2 = 0.f, a3 = 0.f;
        int e = beg;
        for (; e + 8 <= end; e += 8) {
            const int s0 = csr[e + 0];
            const int s1 = csr[e + 1];
            const int s2 = csr[e + 2];
            const int s3 = csr[e + 3];
            const int s4 = csr[e + 4];
            const int s5 = csr[e + 5];
            const int s6 = csr[e + 6];
            const int s7 = csr[e + 7];
            const half8 v0 = src[s0 * 8 + lane];
            const half8 v1 = src[s1 * 8 + lane];
            const half8 v2 = src[s2 * 8 + lane];
            const half8 v3 = src[s3 * 8 + lane];
            const half8 v4 = src[s4 * 8 + lane];
            const half8 v5 = src[s5 * 8 + lane];
            const half8 v6 = src[s6 * 8 + lane];
            const half8 v7 = src[s7 * 8 + lane];
            a0 += h8_to_f8(v0);
            a1 += h8_to_f8(v1);
            a2 += h8_to_f8(v2);
            a3 += h8_to_f8(v3);
            a0 += h8_to_f8(v4);
            a1 += h8_to_f8(v5);
            a2 += h8_to_f8(v6);
            a3 += h8_to_f8(v7);
        }
        if (e < end) {   // exactly one 4-wide iteration (pd % 4 == 0)
            const int s0 = csr[e + 0];
            const int s1 = csr[e + 1];
            const int s2 = csr[e + 2];
            const int s3 = csr[e + 3];
            a0 += h8_to_f8(src[s0 * 8 + lane]);
            a1 += h8_to_f8(src[s1 * 8 + lane]);
            a2 += h8_to_f8(src[s2 * 8 + lane]);
            a3 += h8_to_f8(src[s3 * 8 + lane]);
        }
        float8 s = (a0 + a1) + (a2 + a3);
        s -= (float)(pd - dg) * r0;
        const float inv = 1.f / (float)(dg > 0 ? dg : 1);
        float8 x = s * inv;
        const int o8 = n * 8 + lane;
        if (x_out != nullptr) {
            half8 h;
            for (int k = 0; k < 8; ++k) h[k] = (_Float16)x[k];
            x_out[o8] = h;
        }
        const int fo = n * (D / 4) + lane * 2;
        if (fin_out != nullptr) {
            float8 t = h8_to_f8(ntl(&fin_x1[o8])) + h8_to_f8(ntl(&fin_x2[o8])) + x;
            f32x4 f0 = ntl(&fin_in0[fo + 0]);
            f32x4 f1 = ntl(&fin_in0[fo + 1]);
            f32x4 t0 = {t[0], t[1], t[2], t[3]};
            f32x4 t1 = {t[4], t[5], t[6], t[7]};
            nts(&fin_out[fo + 0], (f0 + t0) * scale);
            nts(&fin_out[fo + 1], (f1 + t1) * scale);
        }
        if (final_acc != nullptr) {
            f32x4 f0, f1;
            if (init_src != nullptr) {
                f0 = init_src[fo + 0] * scale;
                f1 = init_src[fo + 1] * scale;
            } else {
                f0 = final_acc[fo + 0];
                f1 = final_acc[fo + 1];
            }
            f32x4 x0 = {x[0], x[1], x[2], x[3]};
            f32x4 x1 = {x[4], x[5], x[6], x[7]};
            final_acc[fo + 0] = f0 + x0 * scale;
            final_acc[fo + 1] = f1 + x1 * scale;
        }
    }
}

extern "C" void kernel_launch(void* const* d_in, const int* in_sizes, int n_in,
                              void* d_out, int out_size, void* d_ws, size_t ws_size,
                              hipStream_t stream) {
    const float* x_users   = (const float*)d_in[0];
    const float* x_artists = (const float*)d_in[1];
    const int*   a2u       = (const int*)d_in[2];  // row0: artist(src), row1: user(dst)

    const int NU = in_sizes[0] / D;
    const int NA = in_sizes[1] / D;
    const int E  = in_sizes[2] / 2;
    const int* art = a2u;
    const int* usr = a2u + E;

    const float scale = 0.25f;   // 1/(NUM_LAYERS+1)

    const int NBu = (NU + (1 << BSHIFT_U) - 1) >> BSHIFT_U;  // 196
    const int NBa = (NA + (1 << BSHIFT_A) - 1) >> BSHIFT_A;  // 196

    // ---- workspace layout (256B aligned) ----
    char* w = (char*)d_ws;
    size_t off = 0;
    auto alloc = [&](size_t bytes) -> char* {
        char* p = w + off;
        off += (bytes + 255) & ~(size_t)255;
        return p;
    };
    int2* rowdeg_u = (int2*)alloc((size_t)NU * 8);
    int2* rowdeg_a = (int2*)alloc((size_t)NA * 8);
    int* bcur      = (int*)alloc((size_t)(NBu + NBa) * 4);
    int* bcur_u    = bcur;
    int* bcur_a    = bcur + NBu;
    int* csr_u     = (int*)alloc((size_t)NBu * CAPC_U * 4);
    int* csr_a     = (int*)alloc((size_t)NBa * CAPC_A * 4);
    half8* xa_in   = (half8*)alloc((size_t)NA * D * 2);   // fp16 copy of x_artists
    unsigned* part_u = (unsigned*)alloc((size_t)NBu * CAP * 4);
    unsigned* part_a = (unsigned*)alloc((size_t)NBa * CAP * 4);

    const size_t XU = (size_t)NU * D * 2;                 // 25.6 MB
    const size_t XA = (size_t)NA * D * 2;                 // 6.4 MB
    const size_t XUa = (XU + 255) & ~(size_t)255;
    const size_t XAa = (XA + 255) & ~(size_t)255;

    const bool modeA = (off + 3 * XUa) <= ws_size;

    half8* x_u1 = (half8*)alloc(XU);
    half8* x_u2 = modeA ? (half8*)alloc(XU) : x_u1;
    half8* x_u3 = modeA ? (half8*)alloc(XU) : x_u1;
    // x_a buffers overlay the (dead-after-build) part region (19.2MB >= 12.8MB)
    char* part_base = (char*)part_u;
    half8* x_a1 = (half8*)(part_base);
    half8* x_a2 = modeA ? (half8*)(part_base + XAa) : x_a1;

    float* out_u = (float*)d_out;
    float* out_a = out_u + (size_t)NU * D;

    // ---- fp16 conversion + sorted CSR build (direction-split partition) ----
    hipMemsetAsync(bcur, 0, (size_t)(NBu + NBa) * 4, stream);
    cvt_f16_kernel<<<1024, TB, 0, stream>>>((const f32x4*)x_artists, xa_in, NA * D / 8);
    const int nchunks = (E + PCHUNK - 1) / PCHUNK;
    partition_both_kernel<<<2 * nchunks, TB, 0, stream>>>(art, usr, E, bcur_u, bcur_a,
                                                          part_u, part_a, NBu, NBa);
    local_csr_both_kernel<<<NBu + NBa, TB, 0, stream>>>(part_u, part_a, bcur_u, bcur_a,
                                                        rowdeg_u, rowdeg_a,
                                                        csr_u, csr_a, NU, NA, NBu);

    // ---- 3 propagation layers ----
    half8* xu_buf[3] = {x_u1, x_u2, x_u3};
    half8* xa_buf[2] = {x_a1, x_a2};           // l=2 artist writes out only (Mode A)
    const half8* srcA = xa_in;
    for (int l = 0; l < 3; ++l) {
        const bool last = (l == 2);
        // users <- artists
        gather_mean_kernel<<<4096, TB, 0, stream>>>(
            srcA, csr_u, rowdeg_u, xu_buf[l],
            modeA ? nullptr : (f32x4*)out_u,
            (!modeA && l == 0) ? (const f32x4*)x_users : nullptr,
            (modeA && last) ? (const f32x4*)x_users : nullptr,
            (modeA && last) ? x_u1 : nullptr,
            (modeA && last) ? x_u2 : nullptr,
            (modeA && last) ? (f32x4*)out_u : nullptr,
            NU, scale);
        // artists <- users
        gather_mean_kernel<<<2048, TB, 0, stream>>>(
            xu_buf[l], csr_a, rowdeg_a,
            (modeA && last) ? nullptr : (modeA ? xa_buf[l] : x_a1),
            modeA ? nullptr : (f32x4*)out_a,
            (!modeA && l == 0) ? (const f32x4*)x_artists : nullptr,
            (modeA && last) ? (const f32x4*)x_artists : nullptr,
            (modeA && last) ? x_a1 : nullptr,
            (modeA && last) ? x_a2 : nullptr,
            (modeA && last) ? (f32x4*)out_a : nullptr,
            NA, scale);
        srcA = modeA ? xa_buf[l < 2 ? l : 0] : x_a1;
    }
}